// Round 1
// baseline (587.775 us; speedup 1.0000x reference)
//
#include <hip/hip_runtime.h>
#include <hip/hip_bf16.h>

constexpr int B_SZ  = 64;
constexpr int T_SZ  = 2048;
constexpr int E_SZ  = 512;   // ENC (= DEC)
constexpr int N_SZ  = 512;   // KQ + VD concatenated
constexpr int KQ_SZ = 256;
constexpr int VD_SZ = 256;
constexpr float NEG_SLOPE = 0.2f;

typedef __bf16 bf16_t;
typedef __bf16 bf16x8 __attribute__((ext_vector_type(8)));
typedef __bf16 bf16x4 __attribute__((ext_vector_type(4)));
typedef float  f32x4  __attribute__((ext_vector_type(4)));

__device__ __forceinline__ float leaky(float x) { return x >= 0.f ? x : NEG_SLOPE * x; }

// ---------- pass 0: Wt[n][e] = bf16(W[e][n]) (B^T layout), bcat[n] ----------
__global__ void prep_kernel(const float* __restrict__ Wk, const float* __restrict__ Wv,
                            const float* __restrict__ bk, const float* __restrict__ bv,
                            bf16_t* __restrict__ Wt, float* __restrict__ bcat)
{
    int g  = blockIdx.x * 256 + threadIdx.x;  // 65536 threads, 4 elems each
    int n  = g >> 7;                          // 0..511
    int e0 = (g & 127) * 4;
    const float* src = (n < KQ_SZ) ? (Wk + n) : (Wv + (n - KQ_SZ));
    bf16x4 h;
#pragma unroll
    for (int j = 0; j < 4; ++j) h[j] = (bf16_t)src[(size_t)(e0 + j) * KQ_SZ];
    *reinterpret_cast<bf16x4*>(Wt + (size_t)n * E_SZ + e0) = h;
    if (g < N_SZ) bcat[g] = (g < KQ_SZ) ? bk[g] : bv[g - KQ_SZ];
}

// ---------- pass 1: query[b][k] = leaky(dec[b]·Wq[:,k] + bq[k]), fp32 ----------
__global__ void query_kernel(const float* __restrict__ dec, const float* __restrict__ Wq,
                             const float* __restrict__ bq, float* __restrict__ q)
{
    int b = blockIdx.x, k = threadIdx.x;
    __shared__ float ds[E_SZ];
    ds[k]       = dec[b * E_SZ + k];
    ds[k + 256] = dec[b * E_SZ + k + 256];
    __syncthreads();
    float acc = bq[k];
#pragma unroll 8
    for (int e = 0; e < E_SZ; ++e) acc += ds[e] * Wq[(size_t)e * KQ_SZ + k];
    q[b * KQ_SZ + k] = leaky(acc);
}

// ---------- pass 2: KV[b][t][n] = leaky(enc[b] @ Wcat + bcat), bf16 MFMA ----------
constexpr int BM = 128, BN = 128, BK = 64;

__global__ __launch_bounds__(256, 2) void gemm_kv_kernel(
    const float* __restrict__ enc, const bf16_t* __restrict__ Wt,
    const float* __restrict__ bcat, const int* __restrict__ seq_len,
    bf16_t* __restrict__ KV)
{
    const int bid = blockIdx.x;
    const int nb = bid & 3;            // N-tile (fastest: 4 consecutive blocks share A rows)
    const int tb = (bid >> 2) & 15;    // T-tile
    const int b  = bid >> 6;           // batch
    const int len = seq_len[b];
    if (tb * BM >= len) return;        // rows fully masked -> K/V never consumed

    const int tid  = threadIdx.x;
    const int lane = tid & 63;
    const int wid  = tid >> 6;
    const int wm   = wid >> 1;         // 0..1 (row half)
    const int wn   = wid & 1;          // 0..1 (col half)

    __shared__ bf16_t As[BM][BK];      // 16 KB
    __shared__ bf16_t Bs[BN][BK];      // 16 KB  (B^T: [n][k])
    __shared__ float  biasS[BN];

    if (tid < BN) biasS[tid] = bcat[nb * BN + tid];

    const int t0 = tb * BM;
    const size_t encBase = ((size_t)b * T_SZ + t0) * E_SZ;

    float4 aReg[8];
    uint4  bReg[4];

    auto loadA = [&](int ks) {
        const int k0 = ks * BK;
#pragma unroll
        for (int i = 0; i < 8; ++i) {
            int c = tid + i * 256;          // 2048 float4-chunks
            int row = c >> 4, c4 = c & 15;
            aReg[i] = *reinterpret_cast<const float4*>(
                enc + encBase + (size_t)row * E_SZ + k0 + c4 * 4);
        }
    };
    auto loadB = [&](int ks) {
        const int k0 = ks * BK;
#pragma unroll
        for (int i = 0; i < 4; ++i) {
            int c = tid + i * 256;          // 1024 16B-chunks
            int nrow = c >> 3, kc = (c & 7) * 8;
            bReg[i] = *reinterpret_cast<const uint4*>(
                Wt + (size_t)(nb * BN + nrow) * E_SZ + k0 + kc);
        }
    };
    auto writeA = [&]() {
#pragma unroll
        for (int i = 0; i < 8; ++i) {
            int c = tid + i * 256;
            int row = c >> 4, c4 = c & 15;
            bf16x4 h;
            h[0] = (bf16_t)aReg[i].x; h[1] = (bf16_t)aReg[i].y;
            h[2] = (bf16_t)aReg[i].z; h[3] = (bf16_t)aReg[i].w;
            *reinterpret_cast<bf16x4*>(&As[row][c4 * 4]) = h;
        }
    };
    auto writeB = [&]() {
#pragma unroll
        for (int i = 0; i < 4; ++i) {
            int c = tid + i * 256;
            int nrow = c >> 3, kc = (c & 7) * 8;
            *reinterpret_cast<uint4*>(&Bs[nrow][kc]) = bReg[i];
        }
    };

    f32x4 acc[4][4];
#pragma unroll
    for (int m = 0; m < 4; ++m)
#pragma unroll
        for (int n = 0; n < 4; ++n) acc[m][n] = (f32x4){0.f, 0.f, 0.f, 0.f};

    loadA(0); loadB(0);
    for (int ks = 0; ks < E_SZ / BK; ++ks) {
        writeA(); writeB();
        __syncthreads();
        if (ks < E_SZ / BK - 1) { loadA(ks + 1); loadB(ks + 1); }  // prefetch hides under MFMA
#pragma unroll
        for (int s = 0; s < 2; ++s) {
            bf16x8 af[4], bfr[4];
#pragma unroll
            for (int m = 0; m < 4; ++m)
                af[m] = *reinterpret_cast<const bf16x8*>(
                    &As[wm * 64 + m * 16 + (lane & 15)][s * 32 + (lane >> 4) * 8]);
#pragma unroll
            for (int n = 0; n < 4; ++n)
                bfr[n] = *reinterpret_cast<const bf16x8*>(
                    &Bs[wn * 64 + n * 16 + (lane & 15)][s * 32 + (lane >> 4) * 8]);
#pragma unroll
            for (int m = 0; m < 4; ++m)
#pragma unroll
                for (int n = 0; n < 4; ++n)
                    acc[m][n] = __builtin_amdgcn_mfma_f32_16x16x32_bf16(
                        af[m], bfr[n], acc[m][n], 0, 0, 0);
        }
        __syncthreads();
    }

    // epilogue: bias + leaky + bf16 store.  C/D map: col=lane&15, row=(lane>>4)*4+r
#pragma unroll
    for (int m = 0; m < 4; ++m) {
#pragma unroll
        for (int n = 0; n < 4; ++n) {
            int col  = wn * 64 + n * 16 + (lane & 15);
            float bias = biasS[col];
            int rowq = wm * 64 + m * 16 + ((lane >> 4) * 4);
#pragma unroll
            for (int r = 0; r < 4; ++r) {
                float v = leaky(acc[m][n][r] + bias);
                int t = t0 + rowq + r;
                KV[((size_t)b * T_SZ + t) * N_SZ + nb * BN + col] = (bf16_t)v;
            }
        }
    }
}

// ---------- pass 3: energy[b][t] = q[b]·K[b][t] (t < len only) ----------
__global__ void energy_kernel(const bf16_t* __restrict__ KV, const float* __restrict__ q,
                              const int* __restrict__ seq_len, float* __restrict__ energy)
{
    int b = blockIdx.y, c = blockIdx.x, tid = threadIdx.x;
    __shared__ float qs[KQ_SZ];
    qs[tid] = q[b * KQ_SZ + tid];
    __syncthreads();
    int t = c * 256 + tid;
    int len = seq_len[b];
    if (t >= len) return;
    const bf16_t* row = KV + ((size_t)b * T_SZ + t) * N_SZ;
    float acc = 0.f;
#pragma unroll 4
    for (int k = 0; k < KQ_SZ; k += 8) {
        bf16x8 v = *reinterpret_cast<const bf16x8*>(row + k);
#pragma unroll
        for (int j = 0; j < 8; ++j) acc += (float)v[j] * qs[k + j];
    }
    energy[b * T_SZ + t] = acc;
}

// ---------- pass 4: masked softmax (== softmax -> mask -> renorm) ----------
__global__ void softmax_kernel(const float* __restrict__ energy, const int* __restrict__ seq_len,
                               float* __restrict__ score)
{
    const int b = blockIdx.x, tid = threadIdx.x;
    const int lane = tid & 63, wid = tid >> 6;
    const int len = seq_len[b];
    float e[8];
    float m = -1e30f;
#pragma unroll
    for (int i = 0; i < 8; ++i) {
        int t = i * 256 + tid;
        e[i] = (t < len) ? energy[b * T_SZ + t] : -1e30f;
        m = fmaxf(m, e[i]);
    }
#pragma unroll
    for (int o = 32; o > 0; o >>= 1) m = fmaxf(m, __shfl_xor(m, o));
    __shared__ float rm[4], rs[4];
    if (lane == 0) rm[wid] = m;
    __syncthreads();
    m = fmaxf(fmaxf(rm[0], rm[1]), fmaxf(rm[2], rm[3]));
    float p[8], s = 0.f;
#pragma unroll
    for (int i = 0; i < 8; ++i) { p[i] = __expf(e[i] - m); s += p[i]; }
#pragma unroll
    for (int o = 32; o > 0; o >>= 1) s += __shfl_xor(s, o);
    if (lane == 0) rs[wid] = s;
    __syncthreads();
    s = rs[0] + rs[1] + rs[2] + rs[3];
    float inv = 1.0f / s;
#pragma unroll
    for (int i = 0; i < 8; ++i) {
        int t = i * 256 + tid;
        score[b * T_SZ + t] = p[i] * inv;   // exp(-1e30-m)=0 for masked lanes
    }
}

// ---------- pass 5: partial context over 256-row chunks ----------
__global__ void ctx_partial_kernel(const bf16_t* __restrict__ KV, const float* __restrict__ score,
                                   const int* __restrict__ seq_len, float* __restrict__ part)
{
    int b = blockIdx.y, c = blockIdx.x, v = threadIdx.x;
    int len = seq_len[b];
    float acc = 0.f;
    if (c * 256 < len) {
        __shared__ float ss[256];
        ss[v] = score[b * T_SZ + c * 256 + v];
        __syncthreads();
        int tlim = min(256, len - c * 256);
        const bf16_t* base = KV + ((size_t)b * T_SZ + c * 256) * N_SZ + KQ_SZ + v;
#pragma unroll 8
        for (int tt = 0; tt < tlim; ++tt) acc += ss[tt] * (float)base[(size_t)tt * N_SZ];
    }
    part[(b * 8 + c) * VD_SZ + v] = acc;
}

// ---------- pass 6: reduce partials ----------
__global__ void ctx_reduce_kernel(const float* __restrict__ part, float* __restrict__ ctx)
{
    int b = blockIdx.x, v = threadIdx.x;
    float s = 0.f;
#pragma unroll
    for (int c = 0; c < 8; ++c) s += part[(b * 8 + c) * VD_SZ + v];
    ctx[b * VD_SZ + v] = s;
}

extern "C" void kernel_launch(void* const* d_in, const int* in_sizes, int n_in,
                              void* d_out, int out_size, void* d_ws, size_t ws_size,
                              hipStream_t stream)
{
    const float* dec = (const float*)d_in[0];
    const float* enc = (const float*)d_in[1];
    const float* Wq  = (const float*)d_in[2];
    const float* bq  = (const float*)d_in[3];
    const float* Wk  = (const float*)d_in[4];
    const float* bk  = (const float*)d_in[5];
    const float* Wv  = (const float*)d_in[6];
    const float* bv  = (const float*)d_in[7];
    const int* seq_len = (const int*)d_in[8];

    float* out   = (float*)d_out;
    float* score = out;                    // [64][2048]
    float* ctx   = out + B_SZ * T_SZ;      // [64][256]

    char* ws = (char*)d_ws;
    size_t off = 0;
    auto alloc = [&](size_t bytes) { size_t o = off; off += (bytes + 255) & ~(size_t)255; return o; };
    bf16_t* Wt     = (bf16_t*)(ws + alloc((size_t)N_SZ * E_SZ * sizeof(bf16_t)));   // 512 KB
    float*  bcat   = (float* )(ws + alloc((size_t)N_SZ * sizeof(float)));
    float*  q      = (float* )(ws + alloc((size_t)B_SZ * KQ_SZ * sizeof(float)));
    float*  energy = (float* )(ws + alloc((size_t)B_SZ * T_SZ * sizeof(float)));
    float*  part   = (float* )(ws + alloc((size_t)B_SZ * 8 * VD_SZ * sizeof(float)));
    bf16_t* KV     = (bf16_t*)(ws + alloc((size_t)B_SZ * T_SZ * N_SZ * sizeof(bf16_t))); // 134 MB

    prep_kernel       <<<256, 256, 0, stream>>>(Wk, Wv, bk, bv, Wt, bcat);
    query_kernel      <<<B_SZ, 256, 0, stream>>>(dec, Wq, bq, q);
    gemm_kv_kernel    <<<B_SZ * (T_SZ / BM) * (N_SZ / BN), 256, 0, stream>>>(enc, Wt, bcat, seq_len, KV);
    energy_kernel     <<<dim3(T_SZ / 256, B_SZ), 256, 0, stream>>>(KV, q, seq_len, energy);
    softmax_kernel    <<<B_SZ, 256, 0, stream>>>(energy, seq_len, score);
    ctx_partial_kernel<<<dim3(8, B_SZ), 256, 0, stream>>>(KV, score, seq_len, part);
    ctx_reduce_kernel <<<B_SZ, 256, 0, stream>>>(part, ctx);
}

// Round 11
// 539.789 us; speedup vs baseline: 1.0889x; 1.0889x over previous
//
#include <hip/hip_runtime.h>
#include <hip/hip_bf16.h>

constexpr int B_SZ  = 64;
constexpr int T_SZ  = 2048;
constexpr int E_SZ  = 512;   // ENC (= DEC)
constexpr int KQ_SZ = 256;
constexpr int VD_SZ = 256;
constexpr float NEG_SLOPE = 0.2f;

typedef __bf16 bf16_t;
typedef __bf16 bf16x8 __attribute__((ext_vector_type(8)));
typedef __bf16 bf16x4 __attribute__((ext_vector_type(4)));
typedef float  f32x4  __attribute__((ext_vector_type(4)));

__device__ __forceinline__ float leaky(float x) { return x >= 0.f ? x : NEG_SLOPE * x; }

// ---------- pass 0: Wt[n][e] = bf16(W[e][n]) (B^T layout), bcat[n] ----------
__global__ void prep_kernel(const float* __restrict__ Wk, const float* __restrict__ Wv,
                            const float* __restrict__ bk, const float* __restrict__ bv,
                            bf16_t* __restrict__ Wt, float* __restrict__ bcat)
{
    int g  = blockIdx.x * 256 + threadIdx.x;  // 65536 threads, 4 elems each
    int n  = g >> 7;                          // 0..511
    int e0 = (g & 127) * 4;
    const float* src = (n < KQ_SZ) ? (Wk + n) : (Wv + (n - KQ_SZ));
    bf16x4 h;
#pragma unroll
    for (int j = 0; j < 4; ++j) h[j] = (bf16_t)src[(size_t)(e0 + j) * KQ_SZ];
    *reinterpret_cast<bf16x4*>(Wt + (size_t)n * E_SZ + e0) = h;
    if (g < 512) bcat[g] = (g < KQ_SZ) ? bk[g] : bv[g - KQ_SZ];
}

// ---------- pass 1: query[b][k] = leaky(dec[b]·Wq[:,k] + bq[k]), fp32 ----------
__global__ void query_kernel(const float* __restrict__ dec, const float* __restrict__ Wq,
                             const float* __restrict__ bq, float* __restrict__ q)
{
    int b = blockIdx.x, k = threadIdx.x;
    __shared__ float ds[E_SZ];
    ds[k]       = dec[b * E_SZ + k];
    ds[k + 256] = dec[b * E_SZ + k + 256];
    __syncthreads();
    float acc = bq[k];
#pragma unroll 8
    for (int e = 0; e < E_SZ; ++e) acc += ds[e] * Wq[(size_t)e * KQ_SZ + k];
    q[b * KQ_SZ + k] = leaky(acc);
}

// ---------- pass 2: fused projections ----------
// nb in {0,1}: K-columns -> energy[b,t] += q . leaky(enc@Wk+bk)  (no K store)
// nb in {2,3}: V-columns -> Vbuf[b][t][v] = bf16(leaky(enc@Wv+bv))
constexpr int BM = 128, BN = 128, BK = 64;

// LDS: stage As bytes [0,16384) + Bs [16384,32768); epilogue Cs [0, 128*272)
constexpr int CS_STRIDE = 272;   // 256 + 16 pad: breaks bank aliasing on repack
constexpr int SMEM_BYTES = BM * CS_STRIDE;  // 34816 > 32768

__device__ __forceinline__ int swz(int row, int cb) {
    return row * 128 + (cb ^ ((row & 7) << 4));   // XOR bank swizzle, 16B granules
}

__global__ __launch_bounds__(256, 3) void gemm_kv_kernel(
    const float* __restrict__ enc, const bf16_t* __restrict__ Wt,
    const float* __restrict__ bcat, const float* __restrict__ q,
    const int* __restrict__ seq_len,
    bf16_t* __restrict__ Vbuf, float* __restrict__ energy)
{
    // XCD-aware remap: the 4 nb-blocks of one (b,tb) group land on the SAME XCD
    // (w%8 = XCD round-robin); (b,tb) groups round-robin across XCDs for balance.
    const int w   = blockIdx.x;          // 0..4095
    const int xcd = w & 7;
    const int s0  = w >> 3;              // 0..511
    const int nb  = s0 & 3;
    const int g   = (s0 >> 2) * 8 + xcd; // 0..1023 group id
    const int b   = g & 63;
    const int tb  = g >> 6;              // 0..15
    const int len = seq_len[b];
    if (tb * BM >= len) return;          // fully-masked tile: outputs never consumed

    const int tid  = threadIdx.x;
    const int lane = tid & 63;
    const int wid  = tid >> 6;
    const int wm   = wid >> 1;
    const int wn   = wid & 1;

    __shared__ __align__(16) char smem[SMEM_BYTES];
    __shared__ float biasS[128];
    __shared__ float qs[128];

    if (tid < 128) {
        biasS[tid] = bcat[nb * 128 + tid];
        if (nb < 2) qs[tid] = q[b * KQ_SZ + nb * 128 + tid];
    }

    const int t0 = tb * BM;
    const size_t encBase = ((size_t)b * T_SZ + t0) * E_SZ;

    float4 aReg[8];
    uint4  bReg[4];

    auto loadA = [&](int ks) {
        const int k0 = ks * BK;
#pragma unroll
        for (int i = 0; i < 8; ++i) {
            int c = tid + i * 256;
            int row = c >> 4, c4 = c & 15;
            aReg[i] = *reinterpret_cast<const float4*>(
                enc + encBase + (size_t)row * E_SZ + k0 + c4 * 4);
        }
    };
    auto loadB = [&](int ks) {
        const int k0 = ks * BK;
#pragma unroll
        for (int i = 0; i < 4; ++i) {
            int c = tid + i * 256;
            int nrow = c >> 3, kc = (c & 7) * 8;
            bReg[i] = *reinterpret_cast<const uint4*>(
                Wt + (size_t)(nb * BN + nrow) * E_SZ + k0 + kc);
        }
    };
    auto writeA = [&]() {
#pragma unroll
        for (int i = 0; i < 8; ++i) {
            int c = tid + i * 256;
            int row = c >> 4, cb = (c & 15) * 8;
            bf16x4 h;
            h[0] = (bf16_t)aReg[i].x; h[1] = (bf16_t)aReg[i].y;
            h[2] = (bf16_t)aReg[i].z; h[3] = (bf16_t)aReg[i].w;
            *reinterpret_cast<bf16x4*>(smem + swz(row, cb)) = h;
        }
    };
    auto writeB = [&]() {
#pragma unroll
        for (int i = 0; i < 4; ++i) {
            int c = tid + i * 256;
            int nrow = c >> 3, cb = (c & 7) * 16;
            *reinterpret_cast<uint4*>(smem + 16384 + swz(nrow, cb)) = bReg[i];
        }
    };

    f32x4 acc[4][4];
#pragma unroll
    for (int m = 0; m < 4; ++m)
#pragma unroll
        for (int n = 0; n < 4; ++n) acc[m][n] = (f32x4){0.f, 0.f, 0.f, 0.f};

    loadA(0); loadB(0);
    for (int ks = 0; ks < E_SZ / BK; ++ks) {
        writeA(); writeB();
        __syncthreads();
        if (ks < E_SZ / BK - 1) { loadA(ks + 1); loadB(ks + 1); }  // in flight under MFMA
#pragma unroll
        for (int s = 0; s < 2; ++s) {
            bf16x8 af[4], bfr[4];
            const int cb = s * 64 + (lane >> 4) * 16;
#pragma unroll
            for (int m = 0; m < 4; ++m)
                af[m] = *reinterpret_cast<const bf16x8*>(
                    smem + swz(wm * 64 + m * 16 + (lane & 15), cb));
#pragma unroll
            for (int n = 0; n < 4; ++n)
                bfr[n] = *reinterpret_cast<const bf16x8*>(
                    smem + 16384 + swz(wn * 64 + n * 16 + (lane & 15), cb));
#pragma unroll
            for (int m = 0; m < 4; ++m)
#pragma unroll
                for (int n = 0; n < 4; ++n)
                    acc[m][n] = __builtin_amdgcn_mfma_f32_16x16x32_bf16(
                        af[m], bfr[n], acc[m][n], 0, 0, 0);
        }
        __syncthreads();
    }

    // C/D map: col = lane&15 (+n*16+wn*64), row = (lane>>4)*4 + r (+m*16+wm*64)
    if (nb < 2) {
        // ---- energy epilogue: ep[row] = sum_col leaky(acc+bias)*q, no K store ----
        float myval = 0.f;
#pragma unroll
        for (int m = 0; m < 4; ++m) {
#pragma unroll
            for (int r = 0; r < 4; ++r) {
                float v = 0.f;
#pragma unroll
                for (int n = 0; n < 4; ++n) {
                    int col = wn * 64 + n * 16 + (lane & 15);
                    v += leaky(acc[m][n][r] + biasS[col]) * qs[col];
                }
                // all-reduce across the 16 lanes of this quarter-wave
#pragma unroll
                for (int o = 1; o < 16; o <<= 1) v += __shfl_xor(v, o);
                if ((lane & 15) == (m * 4 + r)) myval = v;
            }
        }
        // lane (lane&15)==m*4+r owns row wm*64 + m*16 + (lane>>4)*4 + r
        int mm = (lane & 15) >> 2, rr = lane & 3;
        int row = wm * 64 + mm * 16 + (lane >> 4) * 4 + rr;
        atomicAdd(&energy[b * T_SZ + t0 + row], myval);
    } else {
        // ---- V epilogue: repack via LDS -> coalesced 16B stores ----
#pragma unroll
        for (int m = 0; m < 4; ++m) {
#pragma unroll
            for (int n = 0; n < 4; ++n) {
                int col = wn * 64 + n * 16 + (lane & 15);
                float bias = biasS[col];
#pragma unroll
                for (int r = 0; r < 4; ++r) {
                    int row = wm * 64 + m * 16 + (lane >> 4) * 4 + r;
                    *reinterpret_cast<bf16_t*>(smem + row * CS_STRIDE + (col * 2)) =
                        (bf16_t)leaky(acc[m][n][r] + bias);
                }
            }
        }
        __syncthreads();
        const int row  = tid >> 1;
        const int half = tid & 1;
        const size_t vbase = ((size_t)b * T_SZ + t0 + row) * VD_SZ
                             + (nb - 2) * 128 + half * 64;
#pragma unroll
        for (int i = 0; i < 8; ++i) {
            bf16x8 hv = *reinterpret_cast<const bf16x8*>(
                smem + row * CS_STRIDE + half * 128 + i * 16);
            *reinterpret_cast<bf16x8*>(Vbuf + vbase + i * 8) = hv;
        }
    }
}

// ---------- pass 4: masked softmax (== softmax -> mask -> renorm) ----------
__global__ void softmax_kernel(const float* __restrict__ energy, const int* __restrict__ seq_len,
                               float* __restrict__ score)
{
    const int b = blockIdx.x, tid = threadIdx.x;
    const int lane = tid & 63, wid = tid >> 6;
    const int len = seq_len[b];
    float e[8];
    float m = -1e30f;
#pragma unroll
    for (int i = 0; i < 8; ++i) {
        int t = i * 256 + tid;
        e[i] = (t < len) ? energy[b * T_SZ + t] : -1e30f;
        m = fmaxf(m, e[i]);
    }
#pragma unroll
    for (int o = 32; o > 0; o >>= 1) m = fmaxf(m, __shfl_xor(m, o));
    __shared__ float rm[4], rs[4];
    if (lane == 0) rm[wid] = m;
    __syncthreads();
    m = fmaxf(fmaxf(rm[0], rm[1]), fmaxf(rm[2], rm[3]));
    float p[8], s = 0.f;
#pragma unroll
    for (int i = 0; i < 8; ++i) { p[i] = __expf(e[i] - m); s += p[i]; }
#pragma unroll
    for (int o = 32; o > 0; o >>= 1) s += __shfl_xor(s, o);
    if (lane == 0) rs[wid] = s;
    __syncthreads();
    s = rs[0] + rs[1] + rs[2] + rs[3];
    float inv = 1.0f / s;
#pragma unroll
    for (int i = 0; i < 8; ++i) {
        int t = i * 256 + tid;
        score[b * T_SZ + t] = p[i] * inv;
    }
}

// ---------- pass 5: partial context over 256-row chunks ----------
__global__ void ctx_partial_kernel(const bf16_t* __restrict__ Vbuf, const float* __restrict__ score,
                                   const int* __restrict__ seq_len, float* __restrict__ part)
{
    int b = blockIdx.y, c = blockIdx.x, v = threadIdx.x;
    int len = seq_len[b];
    float acc = 0.f;
    if (c * 256 < len) {
        __shared__ float ss[256];
        ss[v] = score[b * T_SZ + c * 256 + v];
        __syncthreads();
        int tlim = min(256, len - c * 256);
        const bf16_t* base = Vbuf + ((size_t)b * T_SZ + c * 256) * VD_SZ + v;
#pragma unroll 8
        for (int tt = 0; tt < tlim; ++tt) acc += ss[tt] * (float)base[(size_t)tt * VD_SZ];
    }
    part[(b * 8 + c) * VD_SZ + v] = acc;
}

// ---------- pass 6: reduce partials ----------
__global__ void ctx_reduce_kernel(const float* __restrict__ part, float* __restrict__ ctx)
{
    int b = blockIdx.x, v = threadIdx.x;
    float s = 0.f;
#pragma unroll
    for (int c = 0; c < 8; ++c) s += part[(b * 8 + c) * VD_SZ + v];
    ctx[b * VD_SZ + v] = s;
}

extern "C" void kernel_launch(void* const* d_in, const int* in_sizes, int n_in,
                              void* d_out, int out_size, void* d_ws, size_t ws_size,
                              hipStream_t stream)
{
    const float* dec = (const float*)d_in[0];
    const float* enc = (const float*)d_in[1];
    const float* Wq  = (const float*)d_in[2];
    const float* bq  = (const float*)d_in[3];
    const float* Wk  = (const float*)d_in[4];
    const float* bk  = (const float*)d_in[5];
    const float* Wv  = (const float*)d_in[6];
    const float* bv  = (const float*)d_in[7];
    const int* seq_len = (const int*)d_in[8];

    float* out   = (float*)d_out;
    float* score = out;                    // [64][2048]
    float* ctx   = out + B_SZ * T_SZ;      // [64][256]

    char* ws = (char*)d_ws;
    size_t off = 0;
    auto alloc = [&](size_t bytes) { size_t o = off; off += (bytes + 255) & ~(size_t)255; return o; };
    bf16_t* Wt     = (bf16_t*)(ws + alloc((size_t)512 * E_SZ * sizeof(bf16_t)));
    float*  bcat   = (float* )(ws + alloc((size_t)512 * sizeof(float)));
    float*  q      = (float* )(ws + alloc((size_t)B_SZ * KQ_SZ * sizeof(float)));
    float*  energy = (float* )(ws + alloc((size_t)B_SZ * T_SZ * sizeof(float)));
    float*  part   = (float* )(ws + alloc((size_t)B_SZ * 8 * VD_SZ * sizeof(float)));
    bf16_t* Vbuf   = (bf16_t*)(ws + alloc((size_t)B_SZ * T_SZ * VD_SZ * sizeof(bf16_t))); // 67 MB

    hipMemsetAsync(energy, 0, (size_t)B_SZ * T_SZ * sizeof(float), stream);  // atomic target

    prep_kernel       <<<256, 256, 0, stream>>>(Wk, Wv, bk, bv, Wt, bcat);
    query_kernel      <<<B_SZ, 256, 0, stream>>>(dec, Wq, bq, q);
    gemm_kv_kernel    <<<B_SZ * 16 * 4, 256, 0, stream>>>(enc, Wt, bcat, q, seq_len, Vbuf, energy);
    softmax_kernel    <<<B_SZ, 256, 0, stream>>>(energy, seq_len, score);
    ctx_partial_kernel<<<dim3(8, B_SZ), 256, 0, stream>>>(Vbuf, score, seq_len, part);
    ctx_reduce_kernel <<<B_SZ, 256, 0, stream>>>(part, ctx);
}